// Round 1
// baseline (635.514 us; speedup 1.0000x reference)
//
#include <hip/hip_runtime.h>
#include <math.h>

#define NB 2
#define NC 128
#define NN 4096
#define TILE 64
#define FLT_MAX_BITS 0x7F7FFFFFu
#define L2E 1.44269504088896340736f

// Inter-pass state (initialized every call in prep_kernel; no cross-call state).
__device__ float    g_tsqr[NB][NN];
__device__ float    g_ssqr[NB][NN];
__device__ unsigned g_rowmin[NB][NN];  // min over j of D[i,j]  (uint bits of nonneg float)
__device__ unsigned g_colmin[NB][NN];  // min over i of D[i,j]
__device__ float    g_ZA[NB][NN];      // Z_A[j] = sum_i exp(2 - 2 D/colmin_j)
__device__ float    g_ZB[NB][NN];      // Z_B[i] = sum_j exp(2 - 2 D/rowmin_i)
__device__ unsigned g_mA[NB][NN];      // max_j E_A/Z_A  per row i   (uint bits)
__device__ unsigned g_mB[NB][NN];      // max_i E_B/Z_B  per col j

__global__ void prep_kernel(const float* __restrict__ src, const float* __restrict__ tgt) {
    int idx = blockIdx.x * blockDim.x + threadIdx.x;   // 0 .. NB*NN-1
    int b = idx >> 12;
    int i = idx & (NN - 1);
    const float* tp = tgt + (size_t)b * NC * NN + i;
    const float* sp = src + (size_t)b * NC * NN + i;
    float ts = 0.f, ss = 0.f;
    #pragma unroll 8
    for (int ch = 0; ch < NC; ++ch) {
        float tv = tp[(size_t)ch * NN]; ts = fmaf(tv, tv, ts);
        float sv = sp[(size_t)ch * NN]; ss = fmaf(sv, sv, ss);
    }
    g_tsqr[b][i] = ts;  g_ssqr[b][i] = ss;
    g_rowmin[b][i] = FLT_MAX_BITS;  g_colmin[b][i] = FLT_MAX_BITS;
    g_ZA[b][i] = 0.f;  g_ZB[b][i] = 0.f;
    g_mA[b][i] = 0u;   g_mB[b][i] = 0u;
}

// PASS 1: mins.  PASS 2: Z sums.  PASS 3: normalized maxes.
template<int PASS>
__global__ void __launch_bounds__(256) tile_kernel(const float* __restrict__ src,
                                                   const float* __restrict__ tgt) {
    __shared__ float As[NC][TILE];   // target tile: As[k][ii] = T[b][k][i0+ii]
    __shared__ float Bs[NC][TILE];   // source tile
    __shared__ unsigned colu[TILE];
    __shared__ float    colf[TILE];

    int bid = blockIdx.x;
    int b   = bid >> 12;             // 4096 tiles per batch
    int t   = bid & 4095;
    int ti  = t >> 6, tj = t & 63;
    int i0  = ti * TILE, j0 = tj * TILE;
    int tid = threadIdx.x;
    const float* Tb = tgt + (size_t)b * NC * NN;
    const float* Sb = src + (size_t)b * NC * NN;

    // Stage tiles (float4, coalesced: 64 contiguous floats per k-row)
    for (int l = tid; l < NC * TILE / 4; l += 256) {
        int k  = l >> 4;
        int c4 = (l & 15) << 2;
        *(float4*)&As[k][c4] = *(const float4*)(Tb + (size_t)k * NN + i0 + c4);
        *(float4*)&Bs[k][c4] = *(const float4*)(Sb + (size_t)k * NN + j0 + c4);
    }
    if (tid < TILE) {
        if (PASS == 1) colu[tid] = FLT_MAX_BITS;
        if (PASS == 2) colf[tid] = 0.f;
        if (PASS == 3) colu[tid] = 0u;
    }
    __syncthreads();

    int tx = tid & 15, ty = tid >> 4;
    float acc[4][4] = {};
    #pragma unroll 4
    for (int k = 0; k < NC; ++k) {
        float4 av = *(const float4*)&As[k][ty << 2];
        float4 bv = *(const float4*)&Bs[k][tx << 2];
        float a[4]  = {av.x, av.y, av.z, av.w};
        float bb[4] = {bv.x, bv.y, bv.z, bv.w};
        #pragma unroll
        for (int r = 0; r < 4; ++r)
            #pragma unroll
            for (int c = 0; c < 4; ++c)
                acc[r][c] = fmaf(a[r], bb[c], acc[r][c]);
    }

    int ib = i0 + (ty << 2);
    int jb = j0 + (tx << 2);
    float tsq[4], ssq[4];
    #pragma unroll
    for (int r = 0; r < 4; ++r) tsq[r] = g_tsqr[b][ib + r];
    #pragma unroll
    for (int c = 0; c < 4; ++c) ssq[c] = g_ssqr[b][jb + c];

    float d[4][4];
    #pragma unroll
    for (int r = 0; r < 4; ++r)
        #pragma unroll
        for (int c = 0; c < 4; ++c)
            d[r][c] = fmaxf(tsq[r] + ssq[c] - 2.f * acc[r][c], 0.f);

    if (PASS == 1) {
        #pragma unroll
        for (int r = 0; r < 4; ++r) {
            float m = fminf(fminf(d[r][0], d[r][1]), fminf(d[r][2], d[r][3]));
            #pragma unroll
            for (int off = 1; off < 16; off <<= 1) m = fminf(m, __shfl_xor(m, off));
            if (tx == 0) atomicMin(&g_rowmin[b][ib + r], __float_as_uint(m));
        }
        #pragma unroll
        for (int c = 0; c < 4; ++c) {
            float m = fminf(fminf(d[0][c], d[1][c]), fminf(d[2][c], d[3][c]));
            atomicMin(&colu[jb - j0 + c], __float_as_uint(m));
        }
        __syncthreads();
        if (tid < TILE) atomicMin(&g_colmin[b][j0 + tid], colu[tid]);
    }

    if (PASS == 2) {
        float rm[4], cm[4];
        #pragma unroll
        for (int r = 0; r < 4; ++r) rm[r] = __uint_as_float(g_rowmin[b][ib + r]) + 1e-5f;
        #pragma unroll
        for (int c = 0; c < 4; ++c) cm[c] = __uint_as_float(g_colmin[b][jb + c]) + 1e-5f;
        float colsum[4] = {0.f, 0.f, 0.f, 0.f};
        #pragma unroll
        for (int r = 0; r < 4; ++r) {
            float rowsum = 0.f;
            #pragma unroll
            for (int c = 0; c < 4; ++c) {
                float ea = exp2f((2.f - 2.f * d[r][c] / cm[c]) * L2E);
                float eb = exp2f((2.f - 2.f * d[r][c] / rm[r]) * L2E);
                colsum[c] += ea;
                rowsum    += eb;
            }
            #pragma unroll
            for (int off = 1; off < 16; off <<= 1) rowsum += __shfl_xor(rowsum, off);
            if (tx == 0) atomicAdd(&g_ZB[b][ib + r], rowsum);
        }
        #pragma unroll
        for (int c = 0; c < 4; ++c) atomicAdd(&colf[jb - j0 + c], colsum[c]);
        __syncthreads();
        if (tid < TILE) atomicAdd(&g_ZA[b][j0 + tid], colf[tid]);
    }

    if (PASS == 3) {
        float rm[4], cm[4], za[4], zb[4];
        #pragma unroll
        for (int r = 0; r < 4; ++r) {
            rm[r] = __uint_as_float(g_rowmin[b][ib + r]) + 1e-5f;
            zb[r] = g_ZB[b][ib + r];
        }
        #pragma unroll
        for (int c = 0; c < 4; ++c) {
            cm[c] = __uint_as_float(g_colmin[b][jb + c]) + 1e-5f;
            za[c] = g_ZA[b][jb + c];
        }
        float colmax[4] = {0.f, 0.f, 0.f, 0.f};
        #pragma unroll
        for (int r = 0; r < 4; ++r) {
            float rowmax = 0.f;
            #pragma unroll
            for (int c = 0; c < 4; ++c) {
                float ea = exp2f((2.f - 2.f * d[r][c] / cm[c]) * L2E) / za[c];
                float eb = exp2f((2.f - 2.f * d[r][c] / rm[r]) * L2E) / zb[r];
                rowmax    = fmaxf(rowmax, ea);
                colmax[c] = fmaxf(colmax[c], eb);
            }
            #pragma unroll
            for (int off = 1; off < 16; off <<= 1) rowmax = fmaxf(rowmax, __shfl_xor(rowmax, off));
            if (tx == 0) atomicMax(&g_mA[b][ib + r], __float_as_uint(rowmax));
        }
        #pragma unroll
        for (int c = 0; c < 4; ++c) atomicMax(&colu[jb - j0 + c], __float_as_uint(colmax[c]));
        __syncthreads();
        if (tid < TILE) atomicMax(&g_mB[b][j0 + tid], colu[tid]);
    }
}

__global__ void final_kernel(float* __restrict__ out) {
    int tid = threadIdx.x;
    float s[4] = {0.f, 0.f, 0.f, 0.f};
    for (int i = tid; i < NN; i += 256) {
        s[0] += __uint_as_float(g_mA[0][i]);
        s[1] += __uint_as_float(g_mA[1][i]);
        s[2] += __uint_as_float(g_mB[0][i]);
        s[3] += __uint_as_float(g_mB[1][i]);
    }
    __shared__ float red[4][4];
    int lane = tid & 63, w = tid >> 6;
    #pragma unroll
    for (int t = 0; t < 4; ++t) {
        float v = s[t];
        #pragma unroll
        for (int off = 32; off; off >>= 1) v += __shfl_down(v, off);
        if (lane == 0) red[t][w] = v;
    }
    __syncthreads();
    if (tid == 0) {
        float o = 0.f;
        #pragma unroll
        for (int t = 0; t < 4; ++t) {
            float S = (red[t][0] + red[t][1] + red[t][2] + red[t][3]) * (1.f / (float)NN);
            o += -logf(S);
        }
        out[0] = o * 0.25f;
    }
}

extern "C" void kernel_launch(void* const* d_in, const int* in_sizes, int n_in,
                              void* d_out, int out_size, void* d_ws, size_t ws_size,
                              hipStream_t stream) {
    const float* src = (const float*)d_in[0];
    const float* tgt = (const float*)d_in[1];
    (void)in_sizes; (void)n_in; (void)d_ws; (void)ws_size; (void)out_size;

    prep_kernel<<<NB * NN / 256, 256, 0, stream>>>(src, tgt);
    int grid = NB * (NN / TILE) * (NN / TILE);
    tile_kernel<1><<<grid, 256, 0, stream>>>(src, tgt);
    tile_kernel<2><<<grid, 256, 0, stream>>>(src, tgt);
    tile_kernel<3><<<grid, 256, 0, stream>>>(src, tgt);
    final_kernel<<<1, 256, 0, stream>>>((float*)d_out);
}

// Round 2
// 223.445 us; speedup vs baseline: 2.8442x; 2.8442x over previous
//
#include <hip/hip_runtime.h>
#include <math.h>

#define NB 2
#define NC 128
#define NN 4096
#define FLT_MAX_BITS 0x7F7FFFFFu
#define L2E 1.44269504088896340736f

typedef __attribute__((ext_vector_type(8))) short short8;
typedef __attribute__((ext_vector_type(4))) float f32x4;

// bf16 copies, pre-transposed to [n][k] so MFMA fragments are k-contiguous.
__device__ unsigned short g_Tb[NB][NN][NC];
__device__ unsigned short g_Sb[NB][NN][NC];
__device__ float    g_tsqr[NB][NN];
__device__ float    g_ssqr[NB][NN];
__device__ unsigned g_rowmin[NB][NN];
__device__ unsigned g_colmin[NB][NN];
__device__ float    g_ZA[NB][NN];
__device__ float    g_ZB[NB][NN];
__device__ unsigned g_mA[NB][NN];
__device__ unsigned g_mB[NB][NN];
__device__ float    g_D[NB][NN][NN];   // 134 MB materialized distance matrix

__device__ __forceinline__ unsigned f2bf(float f) {
    unsigned u = __float_as_uint(f);
    u += 0x7FFFu + ((u >> 16) & 1u);   // RNE
    return u >> 16;
}

// fp32 [k][n] -> bf16 [n][k], fused with squared-norm computation.
__global__ void __launch_bounds__(256) transpose_prep(const float* __restrict__ src,
                                                      const float* __restrict__ tgt) {
    __shared__ float ls[NC][68];       // padded: col reads conflict-light
    int bid = blockIdx.x;              // 2 mat x 2 b x 64 n-chunks = 256
    int mat = bid >> 7;
    int b   = (bid >> 6) & 1;
    int n0  = (bid & 63) << 6;
    int tid = threadIdx.x;
    const float* in = (mat ? tgt : src) + (size_t)b * NC * NN;
    unsigned short (*out)[NC] = mat ? g_Tb[b] : g_Sb[b];
    float* sq = mat ? g_tsqr[b] : g_ssqr[b];

    for (int idx = tid; idx < NC * 16; idx += 256) {
        int k = idx >> 4, c4 = (idx & 15) << 2;
        *(float4*)&ls[k][c4] = *(const float4*)(in + (size_t)k * NN + n0 + c4);
    }
    __syncthreads();
    // each iteration writes one 16B chunk (8 bf16 k's) of output row n
    for (int ci = tid; ci < 64 * 16; ci += 256) {
        int n = ci & 63, c = ci >> 6;  // n fastest: LDS reads conflict-free
        for (int cc = c; cc < 16; cc += 4) {
            unsigned uo[4];
            #pragma unroll
            for (int e = 0; e < 4; ++e) {
                unsigned lo = f2bf(ls[cc * 8 + 2 * e][n]);
                unsigned hi = f2bf(ls[cc * 8 + 2 * e + 1][n]);
                uo[e] = lo | (hi << 16);
            }
            *(uint4*)&out[n0 + n][cc * 8] = make_uint4(uo[0], uo[1], uo[2], uo[3]);
        }
        break;  // outer loop only provides (n,c) once; inner cc loop covers stride
    }
    // squared norms (fp32, exact)
    if (tid < 64) {
        float s = 0.f;
        #pragma unroll 8
        for (int k = 0; k < NC; ++k) { float v = ls[k][tid]; s = fmaf(v, v, s); }
        sq[n0 + tid] = s;
    }
}

__global__ void init_kernel() {
    int idx = blockIdx.x * 256 + threadIdx.x;   // 32 blocks
    int b = idx >> 12, i = idx & (NN - 1);
    g_rowmin[b][i] = FLT_MAX_BITS;  g_colmin[b][i] = FLT_MAX_BITS;
    g_ZA[b][i] = 0.f;  g_ZB[b][i] = 0.f;
    g_mA[b][i] = 0u;   g_mB[b][i] = 0u;
}

// MFMA GEMM: D = ||t||^2 + ||s||^2 - 2 T^T S, fused row/col-min. No LDS.
__global__ void __launch_bounds__(256) gemm_min_kernel() {
    int bid = blockIdx.x;              // NB*32*32 = 2048
    int b  = bid >> 10;
    int ti = (bid >> 5) & 31, tj = bid & 31;
    int wave = threadIdx.x >> 6, lane = threadIdx.x & 63;
    int q = lane >> 4, x = lane & 15;
    int iw = ti * 128 + (wave >> 1) * 64;
    int jw = tj * 128 + (wave & 1) * 64;

    f32x4 acc[4][4];
    #pragma unroll
    for (int m = 0; m < 4; ++m)
        #pragma unroll
        for (int n = 0; n < 4; ++n)
            acc[m][n] = (f32x4){0.f, 0.f, 0.f, 0.f};

    #pragma unroll
    for (int kk = 0; kk < 4; ++kk) {
        int ko = kk * 32 + q * 8;
        short8 af[4], bfr[4];
        #pragma unroll
        for (int m = 0; m < 4; ++m)
            af[m] = *(const short8*)&g_Tb[b][iw + m * 16 + x][ko];
        #pragma unroll
        for (int n = 0; n < 4; ++n)
            bfr[n] = *(const short8*)&g_Sb[b][jw + n * 16 + x][ko];
        #pragma unroll
        for (int m = 0; m < 4; ++m)
            #pragma unroll
            for (int n = 0; n < 4; ++n)
                acc[m][n] = __builtin_amdgcn_mfma_f32_16x16x32_bf16(af[m], bfr[n], acc[m][n], 0, 0, 0);
    }

    float tq[16], sq4[4];
    #pragma unroll
    for (int m = 0; m < 4; ++m)
        #pragma unroll
        for (int v = 0; v < 4; ++v)
            tq[m * 4 + v] = g_tsqr[b][iw + m * 16 + q * 4 + v];
    #pragma unroll
    for (int n = 0; n < 4; ++n) sq4[n] = g_ssqr[b][jw + n * 16 + x];

    float rmin[16], cmin[4];
    #pragma unroll
    for (int t = 0; t < 16; ++t) rmin[t] = 3.0e38f;
    #pragma unroll
    for (int n = 0; n < 4; ++n) cmin[n] = 3.0e38f;

    #pragma unroll
    for (int m = 0; m < 4; ++m) {
        #pragma unroll
        for (int n = 0; n < 4; ++n) {
            float dv[4];
            #pragma unroll
            for (int v = 0; v < 4; ++v) {
                dv[v] = fmaxf(tq[m * 4 + v] + sq4[n] - 2.f * acc[m][n][v], 0.f);
                g_D[b][iw + m * 16 + q * 4 + v][jw + n * 16 + x] = dv[v];
                rmin[m * 4 + v] = fminf(rmin[m * 4 + v], dv[v]);
            }
            cmin[n] = fminf(cmin[n], fminf(fminf(dv[0], dv[1]), fminf(dv[2], dv[3])));
        }
    }
    // row-min: reduce over lanes 0-15 (same q => same row set, different j)
    #pragma unroll
    for (int off = 1; off < 16; off <<= 1)
        #pragma unroll
        for (int t = 0; t < 16; ++t) rmin[t] = fminf(rmin[t], __shfl_xor(rmin[t], off));
    if (x == 0)
        #pragma unroll
        for (int t = 0; t < 16; ++t)
            atomicMin(&g_rowmin[b][iw + (t >> 2) * 16 + q * 4 + (t & 3)], __float_as_uint(rmin[t]));
    // col-min: reduce over quarter-waves (same x => same col set, different i)
    #pragma unroll
    for (int off = 16; off < 64; off <<= 1)
        #pragma unroll
        for (int n = 0; n < 4; ++n) cmin[n] = fminf(cmin[n], __shfl_xor(cmin[n], off));
    if (q == 0)
        #pragma unroll
        for (int n = 0; n < 4; ++n)
            atomicMin(&g_colmin[b][jw + n * 16 + x], __float_as_uint(cmin[n]));
}

// stream D: Z sums (column-normalizers for both directions)
__global__ void __launch_bounds__(256) pass2_kernel() {
    __shared__ float colf[64];
    int bid = blockIdx.x;              // NB*64*64 = 8192
    int b = bid >> 12;
    int t = bid & 4095;
    int i0 = (t >> 6) << 6, j0 = (t & 63) << 6;
    int tid = threadIdx.x, tx = tid & 15, ty = tid >> 4;
    int ib = i0 + (ty << 2), jb = j0 + (tx << 2);
    if (tid < 64) colf[tid] = 0.f;
    __syncthreads();

    float d[4][4];
    #pragma unroll
    for (int r = 0; r < 4; ++r)
        *(float4*)&d[r][0] = *(const float4*)&g_D[b][ib + r][jb];

    float rr[4], rc[4];
    #pragma unroll
    for (int r = 0; r < 4; ++r) rr[r] = 2.f / (__uint_as_float(g_rowmin[b][ib + r]) + 1e-5f);
    #pragma unroll
    for (int c = 0; c < 4; ++c) rc[c] = 2.f / (__uint_as_float(g_colmin[b][jb + c]) + 1e-5f);

    float colsum[4] = {0.f, 0.f, 0.f, 0.f};
    #pragma unroll
    for (int r = 0; r < 4; ++r) {
        float rowsum = 0.f;
        #pragma unroll
        for (int c = 0; c < 4; ++c) {
            colsum[c] += exp2f((2.f - d[r][c] * rc[c]) * L2E);
            rowsum    += exp2f((2.f - d[r][c] * rr[r]) * L2E);
        }
        #pragma unroll
        for (int off = 1; off < 16; off <<= 1) rowsum += __shfl_xor(rowsum, off);
        if (tx == 0) atomicAdd(&g_ZB[b][ib + r], rowsum);
    }
    #pragma unroll
    for (int c = 0; c < 4; ++c) atomicAdd(&colf[jb - j0 + c], colsum[c]);
    __syncthreads();
    if (tid < 64) atomicAdd(&g_ZA[b][j0 + tid], colf[tid]);
}

// stream D: normalized maxes
__global__ void __launch_bounds__(256) pass3_kernel() {
    __shared__ unsigned colu[64];
    int bid = blockIdx.x;
    int b = bid >> 12;
    int t = bid & 4095;
    int i0 = (t >> 6) << 6, j0 = (t & 63) << 6;
    int tid = threadIdx.x, tx = tid & 15, ty = tid >> 4;
    int ib = i0 + (ty << 2), jb = j0 + (tx << 2);
    if (tid < 64) colu[tid] = 0u;
    __syncthreads();

    float d[4][4];
    #pragma unroll
    for (int r = 0; r < 4; ++r)
        *(float4*)&d[r][0] = *(const float4*)&g_D[b][ib + r][jb];

    float rr[4], rc[4], rza[4], rzb[4];
    #pragma unroll
    for (int r = 0; r < 4; ++r) {
        rr[r]  = 2.f / (__uint_as_float(g_rowmin[b][ib + r]) + 1e-5f);
        rzb[r] = 1.f / g_ZB[b][ib + r];
    }
    #pragma unroll
    for (int c = 0; c < 4; ++c) {
        rc[c]  = 2.f / (__uint_as_float(g_colmin[b][jb + c]) + 1e-5f);
        rza[c] = 1.f / g_ZA[b][jb + c];
    }

    float colmax[4] = {0.f, 0.f, 0.f, 0.f};
    #pragma unroll
    for (int r = 0; r < 4; ++r) {
        float rowmax = 0.f;
        #pragma unroll
        for (int c = 0; c < 4; ++c) {
            float ea = exp2f((2.f - d[r][c] * rc[c]) * L2E) * rza[c];
            float eb = exp2f((2.f - d[r][c] * rr[r]) * L2E) * rzb[r];
            rowmax    = fmaxf(rowmax, ea);
            colmax[c] = fmaxf(colmax[c], eb);
        }
        #pragma unroll
        for (int off = 1; off < 16; off <<= 1) rowmax = fmaxf(rowmax, __shfl_xor(rowmax, off));
        if (tx == 0) atomicMax(&g_mA[b][ib + r], __float_as_uint(rowmax));
    }
    #pragma unroll
    for (int c = 0; c < 4; ++c) atomicMax(&colu[jb - j0 + c], __float_as_uint(colmax[c]));
    __syncthreads();
    if (tid < 64) atomicMax(&g_mB[b][j0 + tid], colu[tid]);
}

__global__ void final_kernel(float* __restrict__ out) {
    int tid = threadIdx.x;
    float s[4] = {0.f, 0.f, 0.f, 0.f};
    for (int i = tid; i < NN; i += 256) {
        s[0] += __uint_as_float(g_mA[0][i]);
        s[1] += __uint_as_float(g_mA[1][i]);
        s[2] += __uint_as_float(g_mB[0][i]);
        s[3] += __uint_as_float(g_mB[1][i]);
    }
    __shared__ float red[4][4];
    int lane = tid & 63, w = tid >> 6;
    #pragma unroll
    for (int t = 0; t < 4; ++t) {
        float v = s[t];
        #pragma unroll
        for (int off = 32; off; off >>= 1) v += __shfl_down(v, off);
        if (lane == 0) red[t][w] = v;
    }
    __syncthreads();
    if (tid == 0) {
        float o = 0.f;
        #pragma unroll
        for (int t = 0; t < 4; ++t) {
            float S = (red[t][0] + red[t][1] + red[t][2] + red[t][3]) * (1.f / (float)NN);
            o += -logf(S);
        }
        out[0] = o * 0.25f;
    }
}

extern "C" void kernel_launch(void* const* d_in, const int* in_sizes, int n_in,
                              void* d_out, int out_size, void* d_ws, size_t ws_size,
                              hipStream_t stream) {
    const float* src = (const float*)d_in[0];
    const float* tgt = (const float*)d_in[1];
    (void)in_sizes; (void)n_in; (void)d_ws; (void)ws_size; (void)out_size;

    transpose_prep<<<256, 256, 0, stream>>>(src, tgt);
    init_kernel<<<32, 256, 0, stream>>>();
    gemm_min_kernel<<<2048, 256, 0, stream>>>();
    pass2_kernel<<<8192, 256, 0, stream>>>();
    pass3_kernel<<<8192, 256, 0, stream>>>();
    final_kernel<<<1, 256, 0, stream>>>((float*)d_out);
}